// Round 1
// baseline (1165.594 us; speedup 1.0000x reference)
//
#include <hip/hip_runtime.h>
#include <math.h>

#define N_NODES 100000
#define N_EDGES 3200000
#define IN_FEAT 256
#define OUT_FEAT 128
#define ALPHA 0.2f

// ---------------- h = x @ W (fp32 vector GEMM) ----------------
// Block: 256 threads, computes 16 rows x 128 cols. x tile staged in LDS.
__global__ __launch_bounds__(256) void gemm_h_kernel(const float* __restrict__ x,
                                                     const float* __restrict__ W,
                                                     float* __restrict__ h) {
  __shared__ float xs[16][IN_FEAT + 4];  // +4 pad: banks k+4r, conflict-free, keeps 16B align
  const int tid = threadIdx.x;
  const int row0 = blockIdx.x * 16;
  // load 16x256 floats = 1024 float4 by 256 threads
  for (int i = tid; i < 16 * IN_FEAT / 4; i += 256) {
    int r = i >> 6;          // (i*4)/256
    int c = (i & 63) << 2;   // (i*4)%256
    float4 v = *(const float4*)(x + (size_t)(row0 + r) * IN_FEAT + c);
    *(float4*)(&xs[r][c]) = v;
  }
  __syncthreads();
  const int tr = tid >> 4;           // 0..15
  const int tc = (tid & 15) << 3;    // 0..120 step 8
  float acc[8] = {0.f, 0.f, 0.f, 0.f, 0.f, 0.f, 0.f, 0.f};
#pragma unroll 4
  for (int k = 0; k < IN_FEAT; ++k) {
    float xv = xs[tr][k];
    float4 w0 = *(const float4*)(W + k * OUT_FEAT + tc);
    float4 w1 = *(const float4*)(W + k * OUT_FEAT + tc + 4);
    acc[0] = fmaf(xv, w0.x, acc[0]);
    acc[1] = fmaf(xv, w0.y, acc[1]);
    acc[2] = fmaf(xv, w0.z, acc[2]);
    acc[3] = fmaf(xv, w0.w, acc[3]);
    acc[4] = fmaf(xv, w1.x, acc[4]);
    acc[5] = fmaf(xv, w1.y, acc[5]);
    acc[6] = fmaf(xv, w1.z, acc[6]);
    acc[7] = fmaf(xv, w1.w, acc[7]);
  }
  float* hp = h + (size_t)(row0 + tr) * OUT_FEAT + tc;
  *(float4*)hp = make_float4(acc[0], acc[1], acc[2], acc[3]);
  *(float4*)(hp + 4) = make_float4(acc[4], acc[5], acc[6], acc[7]);
}

// ---------------- s_src/s_dst = h @ a_src, h @ a_dst (one wave per node) ----------------
__global__ __launch_bounds__(256) void s_kernel(const float* __restrict__ h,
                                                const float* __restrict__ a,
                                                float* __restrict__ s_src,
                                                float* __restrict__ s_dst) {
  const int lane = threadIdx.x & 63;
  const int r = blockIdx.x * 4 + (threadIdx.x >> 6);
  float2 hv = *(const float2*)(h + (size_t)r * OUT_FEAT + lane * 2);
  float2 as = *(const float2*)(a + lane * 2);
  float2 ad = *(const float2*)(a + OUT_FEAT + lane * 2);
  float ds = hv.x * as.x + hv.y * as.y;
  float dd = hv.x * ad.x + hv.y * ad.y;
#pragma unroll
  for (int off = 32; off >= 1; off >>= 1) {
    ds += __shfl_xor(ds, off, 64);
    dd += __shfl_xor(dd, off, 64);
  }
  if (lane == 0) {
    s_src[r] = ds;
    s_dst[r] = dd;
  }
}

// ---------------- CSR build ----------------
__global__ void count_kernel(const int* __restrict__ erow, int* __restrict__ deg) {
  int e = blockIdx.x * blockDim.x + threadIdx.x;
  atomicAdd(&deg[erow[e]], 1);
}

// single-block exclusive scan over N_NODES degrees -> offs[N_NODES+1]
__global__ __launch_bounds__(1024) void scan_kernel(const int* __restrict__ deg,
                                                    int* __restrict__ offs) {
  __shared__ int partial[1024];
  const int t = threadIdx.x;
  const int CH = (N_NODES + 1023) / 1024;  // 98
  const int begin = t * CH;
  const int end = (begin + CH < N_NODES) ? (begin + CH) : N_NODES;
  int sum = 0;
  for (int i = begin; i < end; ++i) sum += deg[i];
  partial[t] = sum;
  __syncthreads();
  for (int d = 1; d < 1024; d <<= 1) {
    int v = (t >= d) ? partial[t - d] : 0;
    __syncthreads();
    partial[t] += v;
    __syncthreads();
  }
  int base = (t == 0) ? 0 : partial[t - 1];
  for (int i = begin; i < end; ++i) {
    offs[i] = base;
    base += deg[i];
  }
  if (begin < N_NODES && end == N_NODES) offs[N_NODES] = base;
}

__global__ void scatter_kernel(const int* __restrict__ erow, const int* __restrict__ ecol,
                               const int* __restrict__ offs, int* __restrict__ cursor,
                               int* __restrict__ scol) {
  int e = blockIdx.x * blockDim.x + threadIdx.x;
  int r = erow[e];
  int pos = offs[r] + atomicAdd(&cursor[r], 1);
  scol[pos] = ecol[e];
}

// ---------------- per-row softmax + aggregation (one wave per row) ----------------
__global__ __launch_bounds__(256) void attn_kernel(const float* __restrict__ h,
                                                   const float* __restrict__ s_src,
                                                   const float* __restrict__ s_dst,
                                                   const int* __restrict__ offs,
                                                   const int* __restrict__ scol,
                                                   float* __restrict__ out) {
  const int lane = threadIdx.x & 63;
  const int r = blockIdx.x * 4 + (threadIdx.x >> 6);
  const int o0 = offs[r];
  const int deg = offs[r + 1] - o0;
  const float ssrc = s_src[r];

  // pass A: row max of leaky-relu scores
  float m = -INFINITY;
  for (int j = lane; j < deg; j += 64) {
    int c = scol[o0 + j];
    float e = ssrc + s_dst[c];
    e = e > 0.f ? e : ALPHA * e;
    m = fmaxf(m, e);
  }
#pragma unroll
  for (int off = 32; off >= 1; off >>= 1) m = fmaxf(m, __shfl_xor(m, off, 64));

  // pass B: sum of exp
  float ssum = 0.f;
  for (int j = lane; j < deg; j += 64) {
    int c = scol[o0 + j];
    float e = ssrc + s_dst[c];
    e = e > 0.f ? e : ALPHA * e;
    ssum += __expf(e - m);
  }
#pragma unroll
  for (int off = 32; off >= 1; off >>= 1) ssum += __shfl_xor(ssum, off, 64);
  const float inv = ssum > 0.f ? 1.0f / ssum : 0.f;

  // pass C: h_prime[r] = sum_j att_j * h[col_j]; lane covers features lane and lane+64
  float a0 = 0.f, a1 = 0.f;
  for (int j = 0; j < deg; ++j) {
    int c = scol[o0 + j];  // uniform across wave -> broadcast
    float e = ssrc + s_dst[c];
    e = e > 0.f ? e : ALPHA * e;
    float att = __expf(e - m) * inv;
    a0 = fmaf(att, h[(size_t)c * OUT_FEAT + lane], a0);
    a1 = fmaf(att, h[(size_t)c * OUT_FEAT + 64 + lane], a1);
  }
  a0 = a0 > 0.f ? a0 : expm1f(a0);
  a1 = a1 > 0.f ? a1 : expm1f(a1);
  out[(size_t)r * OUT_FEAT + lane] = a0;
  out[(size_t)r * OUT_FEAT + 64 + lane] = a1;
}

extern "C" void kernel_launch(void* const* d_in, const int* in_sizes, int n_in,
                              void* d_out, int out_size, void* d_ws, size_t ws_size,
                              hipStream_t stream) {
  const float* x = (const float*)d_in[0];
  const int* erow = (const int*)d_in[1];
  const int* ecol = (const int*)d_in[2];
  const float* W = (const float*)d_in[3];
  const float* a = (const float*)d_in[4];
  float* out = (float*)d_out;

  char* ws = (char*)d_ws;
  size_t off = 0;
  auto alloc = [&](size_t bytes) {
    void* p = ws + off;
    off = (off + bytes + 255) & ~(size_t)255;
    return p;
  };
  float* h = (float*)alloc((size_t)N_NODES * OUT_FEAT * sizeof(float));  // 51.2 MB
  float* s_src = (float*)alloc((size_t)N_NODES * sizeof(float));
  float* s_dst = (float*)alloc((size_t)N_NODES * sizeof(float));
  int* deg = (int*)alloc((size_t)N_NODES * sizeof(int));
  int* offs = (int*)alloc((size_t)(N_NODES + 1) * sizeof(int));
  int* cursor = (int*)alloc((size_t)N_NODES * sizeof(int));
  int* scol = (int*)alloc((size_t)N_EDGES * sizeof(int));  // 12.8 MB

  hipMemsetAsync(deg, 0, (size_t)N_NODES * sizeof(int), stream);
  hipMemsetAsync(cursor, 0, (size_t)N_NODES * sizeof(int), stream);

  gemm_h_kernel<<<N_NODES / 16, 256, 0, stream>>>(x, W, h);          // 100000 % 16 == 0
  s_kernel<<<N_NODES / 4, 256, 0, stream>>>(h, a, s_src, s_dst);     // 100000 % 4 == 0
  count_kernel<<<N_EDGES / 256, 256, 0, stream>>>(erow, deg);        // 3.2M % 256 == 0
  scan_kernel<<<1, 1024, 0, stream>>>(deg, offs);
  scatter_kernel<<<N_EDGES / 256, 256, 0, stream>>>(erow, ecol, offs, cursor, scol);
  attn_kernel<<<N_NODES / 4, 256, 0, stream>>>(h, s_src, s_dst, offs, scol, out);
}

// Round 2
// 682.198 us; speedup vs baseline: 1.7086x; 1.7086x over previous
//
#include <hip/hip_runtime.h>
#include <math.h>

#define N_NODES 100000
#define N_EDGES 3200000
#define IN_FEAT 256
#define OUT_FEAT 128
#define ALPHA 0.2f

typedef __attribute__((ext_vector_type(8))) short short8;
typedef __attribute__((ext_vector_type(4))) float f32x4;

__device__ __forceinline__ ushort f2bf(float f) {
  uint u = __float_as_uint(f);
  u = (u + 0x7FFFu + ((u >> 16) & 1u)) >> 16;  // RNE
  return (ushort)u;
}

// ---------------- W transpose + bf16 cast: Wt[c][k] = bf16(W[k][c]) ----------------
__global__ __launch_bounds__(256) void wt_kernel(const float* __restrict__ W,
                                                 ushort* __restrict__ Wt) {
  int id = blockIdx.x * 256 + threadIdx.x;  // 128*256 total
  int c = id >> 8;
  int k = id & 255;
  Wt[id] = f2bf(W[k * OUT_FEAT + c]);
}

// ---------------- h16 = bf16(x @ W) via MFMA ----------------
// Block: 256 thr (4 waves). Tile M=128 (wave: 32 rows), N=128 full, K-step 32.
#define GBM 128
#define GBK 32
#define A_LD 40   // ushorts per LDS row (32 + 8 pad)
#define C_LD 136  // ushorts per epilogue row (128 + 8 pad, keeps 16B align)

__global__ __launch_bounds__(256) void gemm_h16_kernel(const float* __restrict__ x,
                                                       const ushort* __restrict__ Wt,
                                                       ushort* __restrict__ h16) {
  __shared__ union {
    struct { ushort A[GBM * A_LD]; ushort B[OUT_FEAT * A_LD]; } s;
    ushort C[GBM * C_LD];
  } sm;
  const int tid = threadIdx.x;
  const int row0 = blockIdx.x * GBM;
  const int lane = tid & 63;
  const int wave = tid >> 6;
  const int lr = lane & 15;  // frag row/col index
  const int lg = lane >> 4;  // 4-lane-group -> k chunk / acc row group

  f32x4 acc[2][8];
#pragma unroll
  for (int m = 0; m < 2; ++m)
#pragma unroll
    for (int n = 0; n < 8; ++n) acc[m][n] = (f32x4)(0.f);

  const int sr = tid >> 1;  // staging row 0..127
  const int sh = tid & 1;   // half (16 elems each)
  const bool arow_ok = (row0 + sr) < N_NODES;
  const float* xg = x + (size_t)(row0 + sr) * IN_FEAT + sh * 16;
  const ushort* wg = Wt + sr * IN_FEAT + sh * 16;

  for (int ks = 0; ks < IN_FEAT / GBK; ++ks) {
    // stage A: 128 rows x 32 k fp32 -> bf16 LDS
    float4 f[4];
    if (arow_ok) {
#pragma unroll
      for (int i = 0; i < 4; ++i) f[i] = *(const float4*)(xg + ks * GBK + i * 4);
    } else {
#pragma unroll
      for (int i = 0; i < 4; ++i) f[i] = make_float4(0.f, 0.f, 0.f, 0.f);
    }
#pragma unroll
    for (int i = 0; i < 4; ++i) {
      uint2 p;
      p.x = (uint)f2bf(f[i].x) | ((uint)f2bf(f[i].y) << 16);
      p.y = (uint)f2bf(f[i].z) | ((uint)f2bf(f[i].w) << 16);
      *(uint2*)&sm.s.A[sr * A_LD + sh * 16 + i * 4] = p;
    }
    // stage B: Wt rows (col-major W) 128 x 32 bf16
    {
      short8 b0 = *(const short8*)(wg + ks * GBK);
      short8 b1 = *(const short8*)(wg + ks * GBK + 8);
      *(short8*)&sm.s.B[sr * A_LD + sh * 16] = b0;
      *(short8*)&sm.s.B[sr * A_LD + sh * 16 + 8] = b1;
    }
    __syncthreads();
    short8 af[2], bf[8];
#pragma unroll
    for (int m = 0; m < 2; ++m)
      af[m] = *(const short8*)&sm.s.A[(wave * 32 + m * 16 + lr) * A_LD + lg * 8];
#pragma unroll
    for (int n = 0; n < 8; ++n)
      bf[n] = *(const short8*)&sm.s.B[(n * 16 + lr) * A_LD + lg * 8];
#pragma unroll
    for (int m = 0; m < 2; ++m)
#pragma unroll
      for (int n = 0; n < 8; ++n)
        acc[m][n] = __builtin_amdgcn_mfma_f32_16x16x32_bf16(af[m], bf[n], acc[m][n], 0, 0, 0);
    __syncthreads();
  }

  // epilogue: acc -> bf16 LDS tile (row-major) -> coalesced global
#pragma unroll
  for (int m = 0; m < 2; ++m)
#pragma unroll
    for (int n = 0; n < 8; ++n)
#pragma unroll
      for (int i = 0; i < 4; ++i)
        sm.C[(wave * 32 + m * 16 + lg * 4 + i) * C_LD + n * 16 + lr] = f2bf(acc[m][n][i]);
  __syncthreads();
  {
    int row = tid >> 1;
    if (row0 + row < N_NODES) {
      const ushort* src = &sm.C[row * C_LD + sh * 64];
      ushort* dst = h16 + (size_t)(row0 + row) * OUT_FEAT + sh * 64;
#pragma unroll
      for (int i = 0; i < 8; ++i) *(short8*)(dst + i * 8) = *(const short8*)(src + i * 8);
    }
  }
}

// ---------------- s_src/s_dst = h @ a (one wave per node, h in bf16) ----------------
__global__ __launch_bounds__(256) void s16_kernel(const ushort* __restrict__ h16,
                                                  const float* __restrict__ a,
                                                  float* __restrict__ s_src,
                                                  float* __restrict__ s_dst) {
  const int lane = threadIdx.x & 63;
  const int r = blockIdx.x * 4 + (threadIdx.x >> 6);
  uint v = *(const uint*)(h16 + (size_t)r * OUT_FEAT + lane * 2);
  float h0 = __uint_as_float(v << 16);
  float h1 = __uint_as_float(v & 0xFFFF0000u);
  float2 as = *(const float2*)(a + lane * 2);
  float2 ad = *(const float2*)(a + OUT_FEAT + lane * 2);
  float ds = h0 * as.x + h1 * as.y;
  float dd = h0 * ad.x + h1 * ad.y;
#pragma unroll
  for (int off = 32; off >= 1; off >>= 1) {
    ds += __shfl_xor(ds, off, 64);
    dd += __shfl_xor(dd, off, 64);
  }
  if (lane == 0) {
    s_src[r] = ds;
    s_dst[r] = dd;
  }
}

// ---------------- CSR build ----------------
__global__ void count_kernel(const int* __restrict__ erow, int* __restrict__ deg) {
  int e = blockIdx.x * blockDim.x + threadIdx.x;
  atomicAdd(&deg[erow[e]], 1);
}

__global__ __launch_bounds__(1024) void scan_kernel(const int* __restrict__ deg,
                                                    int* __restrict__ offs) {
  __shared__ int partial[1024];
  const int t = threadIdx.x;
  const int CH = (N_NODES + 1023) / 1024;  // 98
  const int begin = t * CH;
  const int end = (begin + CH < N_NODES) ? (begin + CH) : N_NODES;
  int sum = 0;
  for (int i = begin; i < end; ++i) sum += deg[i];
  partial[t] = sum;
  __syncthreads();
  for (int d = 1; d < 1024; d <<= 1) {
    int v = (t >= d) ? partial[t - d] : 0;
    __syncthreads();
    partial[t] += v;
    __syncthreads();
  }
  int base = (t == 0) ? 0 : partial[t - 1];
  for (int i = begin; i < end; ++i) {
    offs[i] = base;
    base += deg[i];
  }
  if (begin < N_NODES && end == N_NODES) offs[N_NODES] = base;
}

__global__ void scatter_kernel(const int* __restrict__ erow, const int* __restrict__ ecol,
                               const int* __restrict__ offs, int* __restrict__ cursor,
                               int* __restrict__ scol) {
  int e = blockIdx.x * blockDim.x + threadIdx.x;
  int r = erow[e];
  int pos = offs[r] + atomicAdd(&cursor[r], 1);
  scol[pos] = ecol[e];
}

// ---------------- online softmax + aggregation (one wave per row) ----------------
__global__ __launch_bounds__(256) void attn_kernel(const ushort* __restrict__ h16,
                                                   const float* __restrict__ s_src,
                                                   const float* __restrict__ s_dst,
                                                   const int* __restrict__ offs,
                                                   const int* __restrict__ scol,
                                                   float* __restrict__ out) {
  const int lane = threadIdx.x & 63;
  const int r = blockIdx.x * 4 + (threadIdx.x >> 6);
  const int o0 = offs[r];
  const int deg = offs[r + 1] - o0;
  const float ssrc = s_src[r];

  // single online pass: per-lane (m, sum)
  float m = -INFINITY, ssum = 0.f;
  for (int j = lane; j < deg; j += 64) {
    int c = scol[o0 + j];
    float e = ssrc + s_dst[c];
    e = e > 0.f ? e : ALPHA * e;
    float nm = fmaxf(m, e);
    ssum = ssum * __expf(m - nm) + __expf(e - nm);
    m = nm;
  }
#pragma unroll
  for (int off = 32; off >= 1; off >>= 1) {
    float m2 = __shfl_xor(m, off, 64);
    float s2 = __shfl_xor(ssum, off, 64);
    float nm = fmaxf(m, m2);
    float t1 = ssum > 0.f ? ssum * __expf(m - nm) : 0.f;
    float t2 = s2 > 0.f ? s2 * __expf(m2 - nm) : 0.f;
    ssum = t1 + t2;
    m = nm;
  }
  const float inv = ssum > 0.f ? 1.f / ssum : 0.f;

  // aggregation: gather h16 rows (1 dword per lane per edge)
  float a0 = 0.f, a1 = 0.f;
  const ushort* hbase = h16 + lane * 2;
#pragma unroll 4
  for (int j = 0; j < deg; ++j) {
    int c = scol[o0 + j];
    float e = ssrc + s_dst[c];
    e = e > 0.f ? e : ALPHA * e;
    float att = __expf(e - m) * inv;
    uint v = *(const uint*)(hbase + (size_t)c * OUT_FEAT);
    a0 = fmaf(att, __uint_as_float(v << 16), a0);
    a1 = fmaf(att, __uint_as_float(v & 0xFFFF0000u), a1);
  }
  a0 = a0 > 0.f ? a0 : expm1f(a0);
  a1 = a1 > 0.f ? a1 : expm1f(a1);
  *(float2*)(out + (size_t)r * OUT_FEAT + lane * 2) = make_float2(a0, a1);
}

extern "C" void kernel_launch(void* const* d_in, const int* in_sizes, int n_in,
                              void* d_out, int out_size, void* d_ws, size_t ws_size,
                              hipStream_t stream) {
  const float* x = (const float*)d_in[0];
  const int* erow = (const int*)d_in[1];
  const int* ecol = (const int*)d_in[2];
  const float* W = (const float*)d_in[3];
  const float* a = (const float*)d_in[4];
  float* out = (float*)d_out;

  char* ws = (char*)d_ws;
  size_t off = 0;
  auto alloc = [&](size_t bytes) {
    void* p = ws + off;
    off = (off + bytes + 255) & ~(size_t)255;
    return p;
  };
  const int M_PAD = 782 * GBM;  // 100096 rows (padded to tile multiple)
  ushort* h16 = (ushort*)alloc((size_t)M_PAD * OUT_FEAT * sizeof(ushort));  // 25.6 MB
  ushort* Wt = (ushort*)alloc((size_t)IN_FEAT * OUT_FEAT * sizeof(ushort));
  float* s_src = (float*)alloc((size_t)N_NODES * sizeof(float));
  float* s_dst = (float*)alloc((size_t)N_NODES * sizeof(float));
  int* deg = (int*)alloc((size_t)N_NODES * sizeof(int));
  int* offs = (int*)alloc((size_t)(N_NODES + 1) * sizeof(int));
  int* cursor = (int*)alloc((size_t)N_NODES * sizeof(int));
  int* scol = (int*)alloc((size_t)N_EDGES * sizeof(int));  // 12.8 MB

  hipMemsetAsync(deg, 0, (size_t)N_NODES * sizeof(int), stream);
  hipMemsetAsync(cursor, 0, (size_t)N_NODES * sizeof(int), stream);

  wt_kernel<<<(IN_FEAT * OUT_FEAT) / 256, 256, 0, stream>>>(W, Wt);
  gemm_h16_kernel<<<782, 256, 0, stream>>>(x, Wt, h16);
  s16_kernel<<<N_NODES / 4, 256, 0, stream>>>(h16, a, s_src, s_dst);
  count_kernel<<<N_EDGES / 256, 256, 0, stream>>>(erow, deg);
  scan_kernel<<<1, 1024, 0, stream>>>(deg, offs);
  scatter_kernel<<<N_EDGES / 256, 256, 0, stream>>>(erow, ecol, offs, cursor, scol);
  attn_kernel<<<N_NODES / 4, 256, 0, stream>>>(h16, s_src, s_dst, offs, scol, out);
}